// Round 6
// baseline (201.737 us; speedup 1.0000x reference)
//
#include <hip/hip_runtime.h>
#include <math.h>

#define NE 1600000
#define NN 100000
#define NBLK ((NN + 255) / 256)  // 391
// fallback path constants
#define NBKT 391
#define BINCH 8192
#define NBINBLK ((NE + BINCH - 1) / BINCH)  // 196

typedef __attribute__((ext_vector_type(8))) short bf16x8;
typedef __attribute__((ext_vector_type(4))) float f32x4;
typedef __attribute__((ext_vector_type(4))) unsigned int u32x4;

static __device__ inline short f2bf(float f) {
  unsigned u = __float_as_uint(f);
  u += 0x7FFFu + ((u >> 16) & 1u);
  return (short)(u >> 16);
}

static __device__ inline void unpack2(unsigned int u, float& lo, float& hi) {
  lo = __uint_as_float(u << 16);
  hi = __uint_as_float(u & 0xffff0000u);
}

// ---------- shared prep ----------

// W -> bf16 fragment order: Wf[(kt*4+ct)*64*8 + l*8 + i] = W[col][k]
__global__ void k_wprep(const float* __restrict__ W, short* __restrict__ Wf) {
  int j = blockIdx.x * 256 + threadIdx.x;
  if (j < 12 * 4 * 64 * 8) {
    int i = j & 7, l = (j >> 3) & 63, ct = (j >> 9) & 3, kt = j >> 11;
    int col = ct * 16 + (l & 15);
    int k = kt * 32 + (l >> 4) * 8 + i;
    Wf[j] = f2bf(W[col * 384 + k]);
  }
}

__global__ void k_zero(int* __restrict__ cnt) {
  int i = blockIdx.x * 256 + threadIdx.x;
  if (i < NN) cnt[i] = 0;
}

__global__ void k_count(const int* __restrict__ dst, int* __restrict__ cnt) {
  int e = (blockIdx.x * 256 + threadIdx.x) * 4;
  if (e + 4 <= NE) {
    int4 d4 = *(const int4*)(dst + e);
    atomicAdd(&cnt[d4.x], 1);
    atomicAdd(&cnt[d4.y], 1);
    atomicAdd(&cnt[d4.z], 1);
    atomicAdd(&cnt[d4.w], 1);
  } else {
    for (; e < NE; ++e) atomicAdd(&cnt[dst[e]], 1);
  }
}

__global__ void k_scan1(const int* __restrict__ cnt, int* __restrict__ bsum) {
  __shared__ int s[256];
  int t = threadIdx.x, i = blockIdx.x * 256 + t;
  s[t] = (i < NN) ? cnt[i] : 0;
  __syncthreads();
  for (int d = 128; d > 0; d >>= 1) {
    if (t < d) s[t] += s[t + d];
    __syncthreads();
  }
  if (t == 0) bsum[blockIdx.x] = s[0];
}

__global__ void k_scan3(const int* __restrict__ cnt, const int* __restrict__ bsum,
                        int* __restrict__ off, int* __restrict__ cur) {
  __shared__ int pre[256];
  __shared__ int s[256];
  int t = threadIdx.x, b = blockIdx.x, i = b * 256 + t;
  int a = 0;
  for (int j = t; j < b; j += 256) a += bsum[j];
  pre[t] = a;
  __syncthreads();
  for (int d = 128; d > 0; d >>= 1) {
    if (t < d) pre[t] += pre[t + d];
    __syncthreads();
  }
  int base = pre[0];
  int v = (i < NN) ? cnt[i] : 0;
  s[t] = v;
  __syncthreads();
  for (int d = 1; d < 256; d <<= 1) {
    int x = (t >= d) ? s[t - d] : 0;
    __syncthreads();
    s[t] += x;
    __syncthreads();
  }
  int ex = s[t] - v + base;
  if (i < NN) {
    off[i] = ex;
    cur[i] = ex;
  }
  if (i == NN - 1) off[NN] = ex + v;  // == NE
}

// ---------- new fast path: CSR bf16 permute + streaming fused ----------

// One thread per 4 floats (16B) of msg. 8 threads cooperate on one 128B row:
// sequential coalesced read, convert to bf16, scatter-write one FULL 64B line
// per row at its CSR slot.
__global__ __launch_bounds__(256) void k_perm(const float* __restrict__ msg,
                                              const int* __restrict__ dst,
                                              int* __restrict__ cur,
                                              unsigned int* __restrict__ pm) {
  int gid = blockIdx.x * 256 + threadIdx.x;  // [0, NE*8); NE*8 % 256 == 0
  int e = gid >> 3, q = gid & 7;
  f32x4 v = *(const f32x4*)(msg + (size_t)gid * 4);
  int lane = threadIdx.x & 63;
  int p = 0;
  if ((lane & 7) == 0) p = atomicAdd(&cur[dst[e]], 1);
  p = __shfl(p, lane & 56);
  unsigned int u0 =
      (unsigned int)(unsigned short)f2bf(v[0]) | ((unsigned int)(unsigned short)f2bf(v[1]) << 16);
  unsigned int u1 =
      (unsigned int)(unsigned short)f2bf(v[2]) | ((unsigned int)(unsigned short)f2bf(v[3]) << 16);
  *(uint2*)((char*)pm + (size_t)p * 64 + q * 8) = make_uint2(u0, u1);
}

// Streaming fused: pm rows are CSR-ordered, so each node's edges are
// consecutive 64B rows. Lane l: node r=l&15, oct=l>>4 reads its 16B octet
// per edge with a direct (index-free) dwordx4. Stats in f32 registers,
// then MFMA projection against Wf.
__global__ __launch_bounds__(256, 6) void k_fused(const unsigned int* __restrict__ pm,
                                                  const int* __restrict__ off,
                                                  const short* __restrict__ Wf,
                                                  const float* __restrict__ bias,
                                                  float* __restrict__ out) {
  int wid = threadIdx.x >> 6, lane = threadIdx.x & 63;
  int r = lane & 15, oct = lane >> 4;
  int nb = (blockIdx.x * 4 + wid) * 16;
  if (nb >= NN) return;
  int node = nb + r;

  int e0 = off[node], e1 = off[node + 1];

  float sv[8], qv[8], xv[8], nv[8];
#pragma unroll
  for (int i = 0; i < 8; i++) {
    sv[i] = 0.f;
    qv[i] = 0.f;
    xv[i] = -INFINITY;
    nv[i] = INFINITY;
  }

  int p = e0;
  int nfull = (e1 - e0) >> 2;
  for (int it = 0; it < nfull; ++it, p += 4) {
    u32x4 U0 = *(const u32x4*)(pm + (size_t)p * 16 + oct * 4);
    u32x4 U1 = *(const u32x4*)(pm + (size_t)(p + 1) * 16 + oct * 4);
    u32x4 U2 = *(const u32x4*)(pm + (size_t)(p + 2) * 16 + oct * 4);
    u32x4 U3 = *(const u32x4*)(pm + (size_t)(p + 3) * 16 + oct * 4);
#pragma unroll
    for (int j = 0; j < 4; j++) {
      float a0, b0, a1, b1, a2, b2, a3, b3;
      unpack2(U0[j], a0, b0);
      unpack2(U1[j], a1, b1);
      unpack2(U2[j], a2, b2);
      unpack2(U3[j], a3, b3);
      int i0 = 2 * j, i1 = 2 * j + 1;
      sv[i0] += a0 + a1 + a2 + a3;
      qv[i0] += a0 * a0 + a1 * a1 + a2 * a2 + a3 * a3;
      xv[i0] = fmaxf(fmaxf(xv[i0], fmaxf(a0, a1)), fmaxf(a2, a3));
      nv[i0] = fminf(fminf(nv[i0], fminf(a0, a1)), fminf(a2, a3));
      sv[i1] += b0 + b1 + b2 + b3;
      qv[i1] += b0 * b0 + b1 * b1 + b2 * b2 + b3 * b3;
      xv[i1] = fmaxf(fmaxf(xv[i1], fmaxf(b0, b1)), fmaxf(b2, b3));
      nv[i1] = fminf(fminf(nv[i1], fminf(b0, b1)), fminf(b2, b3));
    }
  }
  for (; p < e1; ++p) {
    u32x4 U = *(const u32x4*)(pm + (size_t)p * 16 + oct * 4);
#pragma unroll
    for (int j = 0; j < 4; j++) {
      float a, b;
      unpack2(U[j], a, b);
      int i0 = 2 * j, i1 = 2 * j + 1;
      sv[i0] += a;
      qv[i0] += a * a;
      xv[i0] = fmaxf(xv[i0], a);
      nv[i0] = fminf(nv[i0], a);
      sv[i1] += b;
      qv[i1] += b * b;
      xv[i1] = fmaxf(xv[i1], b);
      nv[i1] = fminf(nv[i1], b);
    }
  }

  float degr = (float)(e1 - e0);
  float deg = fmaxf(degr, 1.f);
  float inv = 1.f / deg;
  float amp = logf(deg + 1.f);
  float att = 1.f / (deg + 1.f);

#pragma unroll
  for (int i = 0; i < 8; i++) {
    float me = sv[i] * inv;
    float va = fmaxf(qv[i] * inv - me * me, 0.f);
    sv[i] = me;                 // mean
    qv[i] = sqrtf(va + 1e-8f);  // std
    xv[i] = (xv[i] == -INFINITY) ? 0.f : xv[i];
    nv[i] = (nv[i] == INFINITY) ? 0.f : nv[i];
  }

  f32x4 acc[4] = {{0.f, 0.f, 0.f, 0.f},
                  {0.f, 0.f, 0.f, 0.f},
                  {0.f, 0.f, 0.f, 0.f},
                  {0.f, 0.f, 0.f, 0.f}};
  float scal[3] = {1.f, amp, att};
  const bf16x8* Bp = (const bf16x8*)Wf;
#pragma unroll
  for (int kt = 0; kt < 12; kt++) {
    const float* ag = (kt < 3) ? sv : (kt < 6) ? xv : (kt < 9) ? nv : qv;
    float sc = scal[kt % 3];
    bf16x8 b0 = Bp[(kt * 4 + 0) * 64 + lane];
    bf16x8 b1 = Bp[(kt * 4 + 1) * 64 + lane];
    bf16x8 b2 = Bp[(kt * 4 + 2) * 64 + lane];
    bf16x8 b3 = Bp[(kt * 4 + 3) * 64 + lane];
    bf16x8 af;
#pragma unroll
    for (int i = 0; i < 8; i++) af[i] = f2bf(ag[i] * sc);
    acc[0] = __builtin_amdgcn_mfma_f32_16x16x32_bf16(af, b0, acc[0], 0, 0, 0);
    acc[1] = __builtin_amdgcn_mfma_f32_16x16x32_bf16(af, b1, acc[1], 0, 0, 0);
    acc[2] = __builtin_amdgcn_mfma_f32_16x16x32_bf16(af, b2, acc[2], 0, 0, 0);
    acc[3] = __builtin_amdgcn_mfma_f32_16x16x32_bf16(af, b3, acc[3], 0, 0, 0);
    __builtin_amdgcn_sched_barrier(0);
  }

#pragma unroll
  for (int ct = 0; ct < 4; ct++) {
    int ocol = ct * 16 + r;
    float bb = bias[ocol];
#pragma unroll
    for (int j = 0; j < 4; j++) {
      int orow = nb + oct * 4 + j;
      out[orow * 64 + ocol] = acc[ct][j] + bb;
    }
  }
}

// ---------- fallback path (round-5 pipeline, used if ws too small) ----------

__global__ void k_init0(int* __restrict__ bktcnt) {
  int t = threadIdx.x;
  if (t < NBKT) bktcnt[t] = 0;
}

__global__ __launch_bounds__(256) void k_bktcount(const int* __restrict__ dst,
                                                  int* __restrict__ bktcnt) {
  __shared__ int hist[NBKT];
  int t = threadIdx.x;
  for (int j = t; j < NBKT; j += 256) hist[j] = 0;
  __syncthreads();
  int start = blockIdx.x * BINCH;
  int lim = min(BINCH, NE - start);
  for (int j = t; j < lim; j += 256) atomicAdd(&hist[dst[start + j] >> 8], 1);
  __syncthreads();
  for (int j = t; j < NBKT; j += 256) {
    int h = hist[j];
    if (h) atomicAdd(&bktcnt[j], h);
  }
}

__global__ void k_bktscan(const int* __restrict__ bktcnt, int* __restrict__ bktoff,
                          int* __restrict__ bkcur, int* __restrict__ off) {
  __shared__ int s[512];
  int t = threadIdx.x;
  int v = (t < NBKT) ? bktcnt[t] : 0;
  s[t] = v;
  __syncthreads();
  for (int d = 1; d < 512; d <<= 1) {
    int x = (t >= d) ? s[t - d] : 0;
    __syncthreads();
    s[t] += x;
    __syncthreads();
  }
  if (t < NBKT) {
    int ex = s[t] - v;
    bktoff[t] = ex;
    bkcur[t] = ex;
  }
  if (t == 0) {
    bktoff[NBKT] = NE;
    off[NN] = NE;
  }
}

__global__ __launch_bounds__(256) void k_bin(const int* __restrict__ dst,
                                             int* __restrict__ bkcur,
                                             int2* __restrict__ pairs) {
  __shared__ int sdst[BINCH];
  __shared__ int hist[NBKT];
  int t = threadIdx.x;
  int start = blockIdx.x * BINCH;
  int lim = min(BINCH, NE - start);
  for (int j = t; j < NBKT; j += 256) hist[j] = 0;
  __syncthreads();
  for (int j = t; j < lim; j += 256) {
    int d = dst[start + j];
    sdst[j] = d;
    atomicAdd(&hist[d >> 8], 1);
  }
  __syncthreads();
  for (int j = t; j < NBKT; j += 256) {
    int h = hist[j];
    hist[j] = h ? atomicAdd(&bkcur[j], h) : 0;
  }
  __syncthreads();
  for (int j = t; j < lim; j += 256) {
    int d = sdst[j];
    int q = atomicAdd(&hist[d >> 8], 1);
    pairs[q] = make_int2(d, start + j);
  }
}

__global__ __launch_bounds__(256) void k_build(const int2* __restrict__ pairs,
                                               const int* __restrict__ bktoff,
                                               int* __restrict__ off,
                                               int* __restrict__ eid) {
  __shared__ int cnt[256];
  __shared__ int loc[256];
  int b = blockIdx.x, t = threadIdx.x;
  int base = bktoff[b];
  int m = bktoff[b + 1] - base;
  cnt[t] = 0;
  __syncthreads();
  for (int i = t; i < m; i += 256) atomicAdd(&cnt[pairs[base + i].x & 255], 1);
  __syncthreads();
  int v = cnt[t];
  loc[t] = v;
  __syncthreads();
  for (int d = 1; d < 256; d <<= 1) {
    int x = (t >= d) ? loc[t - d] : 0;
    __syncthreads();
    loc[t] += x;
    __syncthreads();
  }
  int ex = base + loc[t] - v;
  int node = b * 256 + t;
  if (node < NN) off[node] = ex;
  __syncthreads();
  loc[t] = ex;
  __syncthreads();
  for (int i = t; i < m; i += 256) {
    int2 pe = pairs[base + i];
    int pdst = atomicAdd(&loc[pe.x & 255], 1);
    eid[pdst] = pe.y;
  }
}

__global__ __launch_bounds__(256, 6) void k_fusedg(const float* __restrict__ msg,
                                                   const int* __restrict__ off,
                                                   const int* __restrict__ eid,
                                                   const short* __restrict__ Wf,
                                                   const float* __restrict__ bias,
                                                   float* __restrict__ out) {
  int wid = threadIdx.x >> 6, lane = threadIdx.x & 63;
  int r = lane & 15, oct = lane >> 4;
  int nb = (blockIdx.x * 4 + wid) * 16;
  if (nb >= NN) return;
  int node = nb + r;

  int e0 = off[node], e1 = off[node + 1];

  float sv[8], qv[8], xv[8], nv[8];
#pragma unroll
  for (int i = 0; i < 8; i++) {
    sv[i] = 0.f;
    qv[i] = 0.f;
    xv[i] = -INFINITY;
    nv[i] = INFINITY;
  }

  const float* mbase = msg + oct * 8;
  for (int p = e0; p < e1; ++p) {
    int e = eid[p];
    const f32x4* rp = (const f32x4*)(mbase + (size_t)e * 32);
    f32x4 a = rp[0], b = rp[1];
#pragma unroll
    for (int i = 0; i < 4; i++) {
      float v0 = a[i], v1 = b[i];
      sv[i] += v0;
      qv[i] += v0 * v0;
      xv[i] = fmaxf(xv[i], v0);
      nv[i] = fminf(nv[i], v0);
      sv[i + 4] += v1;
      qv[i + 4] += v1 * v1;
      xv[i + 4] = fmaxf(xv[i + 4], v1);
      nv[i + 4] = fminf(nv[i + 4], v1);
    }
  }

  float degr = (float)(e1 - e0);
  float deg = fmaxf(degr, 1.f);
  float inv = 1.f / deg;
  float amp = logf(deg + 1.f);
  float att = 1.f / (deg + 1.f);

#pragma unroll
  for (int i = 0; i < 8; i++) {
    float me = sv[i] * inv;
    float va = fmaxf(qv[i] * inv - me * me, 0.f);
    sv[i] = me;
    qv[i] = sqrtf(va + 1e-8f);
    xv[i] = (xv[i] == -INFINITY) ? 0.f : xv[i];
    nv[i] = (nv[i] == INFINITY) ? 0.f : nv[i];
  }

  f32x4 acc[4] = {{0.f, 0.f, 0.f, 0.f},
                  {0.f, 0.f, 0.f, 0.f},
                  {0.f, 0.f, 0.f, 0.f},
                  {0.f, 0.f, 0.f, 0.f}};
  float scal[3] = {1.f, amp, att};
  const bf16x8* Bp = (const bf16x8*)Wf;
#pragma unroll
  for (int kt = 0; kt < 12; kt++) {
    const float* ag = (kt < 3) ? sv : (kt < 6) ? xv : (kt < 9) ? nv : qv;
    float sc = scal[kt % 3];
    bf16x8 b0 = Bp[(kt * 4 + 0) * 64 + lane];
    bf16x8 b1 = Bp[(kt * 4 + 1) * 64 + lane];
    bf16x8 b2 = Bp[(kt * 4 + 2) * 64 + lane];
    bf16x8 b3 = Bp[(kt * 4 + 3) * 64 + lane];
    bf16x8 af;
#pragma unroll
    for (int i = 0; i < 8; i++) af[i] = f2bf(ag[i] * sc);
    acc[0] = __builtin_amdgcn_mfma_f32_16x16x32_bf16(af, b0, acc[0], 0, 0, 0);
    acc[1] = __builtin_amdgcn_mfma_f32_16x16x32_bf16(af, b1, acc[1], 0, 0, 0);
    acc[2] = __builtin_amdgcn_mfma_f32_16x16x32_bf16(af, b2, acc[2], 0, 0, 0);
    acc[3] = __builtin_amdgcn_mfma_f32_16x16x32_bf16(af, b3, acc[3], 0, 0, 0);
    __builtin_amdgcn_sched_barrier(0);
  }

#pragma unroll
  for (int ct = 0; ct < 4; ct++) {
    int ocol = ct * 16 + r;
    float bb = bias[ocol];
#pragma unroll
    for (int j = 0; j < 4; j++) {
      int orow = nb + oct * 4 + j;
      out[orow * 64 + ocol] = acc[ct][j] + bb;
    }
  }
}

// ---------- launcher ----------

extern "C" void kernel_launch(void* const* d_in, const int* in_sizes, int n_in,
                              void* d_out, int out_size, void* d_ws, size_t ws_size,
                              hipStream_t stream) {
  const float* msg = (const float*)d_in[0];
  const int* dst = (const int*)d_in[1];
  const float* W = (const float*)d_in[3];
  const float* bias = (const float*)d_in[4];
  float* out = (float*)d_out;

  const size_t NEWWS = (size_t)NE * 64 + (size_t)(3 * NN + 1 + NBLK) * 4 + (size_t)24576 * 2;

  if (ws_size >= NEWWS) {
    // fast path: CSR bf16 permute + streaming fused
    unsigned int* pm = (unsigned int*)d_ws;        // NE*16 uints (64B/row)
    int* cnt = (int*)(pm + (size_t)NE * 16);       // NN
    int* off = cnt + NN;                           // NN+1
    int* cur = off + NN + 1;                       // NN
    int* bsum = cur + NN;                          // NBLK
    short* Wfrag = (short*)(bsum + NBLK);          // 24576 shorts

    k_wprep<<<96, 256, 0, stream>>>(W, Wfrag);
    k_zero<<<NBLK, 256, 0, stream>>>(cnt);
    k_count<<<(NE / 4 + 255) / 256, 256, 0, stream>>>(dst, cnt);
    k_scan1<<<NBLK, 256, 0, stream>>>(cnt, bsum);
    k_scan3<<<NBLK, 256, 0, stream>>>(cnt, bsum, off, cur);
    k_perm<<<NE * 8 / 256, 256, 0, stream>>>(msg, dst, cur, pm);
    k_fused<<<(NN / 16 + 3) / 4, 256, 0, stream>>>(pm, off, Wfrag, bias, out);
  } else {
    // fallback: round-5 bucket pipeline
    int* wsi = (int*)d_ws;
    int2* pairs = (int2*)wsi;               // 2*NE ints
    int* eid = wsi + 2 * NE;                // NE
    int* off = wsi + 3 * NE;                // NN+1
    int* bktcnt = wsi + 3 * NE + NN + 1;    // NBKT
    int* bktoff = bktcnt + NBKT;            // NBKT+1
    int* bkcur = bktoff + NBKT + 1;         // NBKT
    short* Wfrag = (short*)(bkcur + NBKT);  // 24576 shorts

    k_init0<<<1, 512, 0, stream>>>(bktcnt);
    k_wprep<<<96, 256, 0, stream>>>(W, Wfrag);
    k_bktcount<<<NBINBLK, 256, 0, stream>>>(dst, bktcnt);
    k_bktscan<<<1, 512, 0, stream>>>(bktcnt, bktoff, bkcur, off);
    k_bin<<<NBINBLK, 256, 0, stream>>>(dst, bkcur, pairs);
    k_build<<<NBKT, 256, 0, stream>>>(pairs, bktoff, off, eid);
    k_fusedg<<<(NN / 16 + 3) / 4, 256, 0, stream>>>(msg, off, eid, Wfrag, bias, out);
  }
}

// Round 7
// 176.833 us; speedup vs baseline: 1.1408x; 1.1408x over previous
//
#include <hip/hip_runtime.h>
#include <math.h>

#define NE 1600000
#define NN 100000
#define NBKT 391    // ceil(NN/256): 256-node buckets
#define PCH 6250    // edges per k_binpay block: 256 * 6250 == NE exactly
#define CBIN 8192
#define NCBLK ((NE + CBIN - 1) / CBIN)  // 196

typedef __attribute__((ext_vector_type(8))) short bf16x8;
typedef __attribute__((ext_vector_type(4))) float f32x4;
typedef __attribute__((ext_vector_type(4))) unsigned int u32x4;

static __device__ inline short f2bf(float f) {
  unsigned u = __float_as_uint(f);
  u += 0x7FFFu + ((u >> 16) & 1u);
  return (short)(u >> 16);
}

static __device__ inline unsigned int pack2(float a, float b) {
  return (unsigned int)(unsigned short)f2bf(a) | ((unsigned int)(unsigned short)f2bf(b) << 16);
}

static __device__ inline void unpack2(unsigned int u, float& lo, float& hi) {
  lo = __uint_as_float(u << 16);
  hi = __uint_as_float(u & 0xffff0000u);
}

// W -> bf16 fragment order: Wf[(kt*4+ct)*64*8 + l*8 + i] = W[col][k]
__global__ void k_wprep(const float* __restrict__ W, short* __restrict__ Wf) {
  int j = blockIdx.x * 256 + threadIdx.x;
  if (j < 12 * 4 * 64 * 8) {
    int i = j & 7, l = (j >> 3) & 63, ct = (j >> 9) & 3, kt = j >> 11;
    int col = ct * 16 + (l & 15);
    int k = kt * 32 + (l >> 4) * 8 + i;
    Wf[j] = f2bf(W[col * 384 + k]);
  }
}

__global__ void k_zerob(int* __restrict__ bktcnt) {
  int t = threadIdx.x;
  if (t < NBKT) bktcnt[t] = 0;
}

// Coarse histogram over 256-node buckets: LDS hist, one global atomic/bucket.
__global__ __launch_bounds__(256) void k_bktcount(const int* __restrict__ dst,
                                                  int* __restrict__ bktcnt) {
  __shared__ int hist[NBKT];
  int t = threadIdx.x;
  for (int j = t; j < NBKT; j += 256) hist[j] = 0;
  __syncthreads();
  int start = blockIdx.x * CBIN;
  int lim = min(CBIN, NE - start);
  for (int j = t; j < lim; j += 256) atomicAdd(&hist[dst[start + j] >> 8], 1);
  __syncthreads();
  for (int j = t; j < NBKT; j += 256) {
    int h = hist[j];
    if (h) atomicAdd(&bktcnt[j], h);
  }
}

// Scan 391 bucket counts -> region bases + cursors.
__global__ void k_bktscan(const int* __restrict__ bktcnt, int* __restrict__ bktoff,
                          int* __restrict__ bkcur, int* __restrict__ off) {
  __shared__ int s[512];
  int t = threadIdx.x;
  int v = (t < NBKT) ? bktcnt[t] : 0;
  s[t] = v;
  __syncthreads();
  for (int d = 1; d < 512; d <<= 1) {
    int x = (t >= d) ? s[t - d] : 0;
    __syncthreads();
    s[t] += x;
    __syncthreads();
  }
  if (t < NBKT) {
    int ex = s[t] - v;
    bktoff[t] = ex;
    bkcur[t] = ex;
  }
  if (t == 0) {
    bktoff[NBKT] = NE;
    off[NN] = NE;
  }
}

// Payload binning: stream msg coalesced, convert to bf16 (64B rows), write rows
// into per-bucket regions. Block reserves per-bucket space once (runs of ~16
// consecutive rows = 1KB bursts), so writes are burst-dense, never random
// single lines. Grid = 256 blocks exactly (one per CU), 768 threads.
__global__ __launch_bounds__(768) void k_binpay(const float* __restrict__ msg,
                                                const int* __restrict__ dst,
                                                int* __restrict__ bkcur,
                                                unsigned int* __restrict__ pay,
                                                int* __restrict__ pdst) {
  __shared__ int sdst[PCH];
  __shared__ int hist[NBKT];
  int t = threadIdx.x;
  int start = blockIdx.x * PCH;  // start+PCH <= NE (exact division)
  for (int j = t; j < NBKT; j += 768) hist[j] = 0;
  __syncthreads();
  for (int j = t; j < PCH; j += 768) {
    int d = dst[start + j];
    sdst[j] = d;
    atomicAdd(&hist[d >> 8], 1);
  }
  __syncthreads();
  for (int j = t; j < NBKT; j += 768) {
    int h = hist[j];
    hist[j] = h ? atomicAdd(&bkcur[j], h) : 0;  // hist becomes global cursor
  }
  __syncthreads();
  int qt = t & 7;        // quarter of the 128B source row / 64B dest row
  int lane = t & 63;
  for (int eb = t >> 3; eb < PCH; eb += 96) {  // 96 edges per round
    int n = sdst[eb];
    int q = 0;
    if (qt == 0) q = atomicAdd(&hist[n >> 8], 1);
    q = __shfl(q, lane & 56);  // broadcast within the 8-lane octet
    f32x4 v = *(const f32x4*)(msg + (size_t)(start + eb) * 32 + qt * 4);
    unsigned int u0 = pack2(v[0], v[1]);
    unsigned int u1 = pack2(v[2], v[3]);
    *(uint2*)(pay + (size_t)q * 16 + qt * 2) = make_uint2(u0, u1);
    if (qt == 0) pdst[q] = n;
  }
}

// One block per bucket: per-node count+scan in LDS, off[] written contiguously,
// eid[p] = pay-row index, scattered within the bucket's 16KB window.
__global__ __launch_bounds__(256) void k_build(const int* __restrict__ pdst,
                                               const int* __restrict__ bktoff,
                                               int* __restrict__ off,
                                               int* __restrict__ eid) {
  __shared__ int cnt[256];
  __shared__ int loc[256];
  int b = blockIdx.x, t = threadIdx.x;
  int base = bktoff[b];
  int m = bktoff[b + 1] - base;
  cnt[t] = 0;
  __syncthreads();
  for (int i = t; i < m; i += 256) atomicAdd(&cnt[pdst[base + i] & 255], 1);
  __syncthreads();
  int v = cnt[t];
  loc[t] = v;
  __syncthreads();
  for (int d = 1; d < 256; d <<= 1) {
    int x = (t >= d) ? loc[t - d] : 0;
    __syncthreads();
    loc[t] += x;
    __syncthreads();
  }
  int ex = base + loc[t] - v;
  int node = b * 256 + t;
  if (node < NN) off[node] = ex;
  __syncthreads();
  loc[t] = ex;
  __syncthreads();
  for (int i = t; i < m; i += 256) {
    int n = pdst[base + i];
    int p = atomicAdd(&loc[n & 255], 1);
    eid[p] = base + i;  // pay row index
  }
}

// Fused gather + stats + MFMA. Gathers 64B bf16 rows from pay via eid; all of
// a wave's reads fall inside its own bucket's ~262KB region (window-local).
// Wave = 16 nodes; lane l: node r=l&15, channel octet oct=l>>4.
__global__ __launch_bounds__(256, 6) void k_fusedS(const unsigned int* __restrict__ pay,
                                                   const int* __restrict__ off,
                                                   const int* __restrict__ eid,
                                                   const short* __restrict__ Wf,
                                                   const float* __restrict__ bias,
                                                   float* __restrict__ out) {
  int wid = threadIdx.x >> 6, lane = threadIdx.x & 63;
  int r = lane & 15, oct = lane >> 4;
  int nb = (blockIdx.x * 4 + wid) * 16;
  if (nb >= NN) return;
  int node = nb + r;

  int e0 = off[node], e1 = off[node + 1];

  float sv[8], qv[8], xv[8], nv[8];
#pragma unroll
  for (int i = 0; i < 8; i++) {
    sv[i] = 0.f;
    qv[i] = 0.f;
    xv[i] = -INFINITY;
    nv[i] = INFINITY;
  }

  int p = e0;
  int nfull = (e1 - e0) >> 2;
  int ea0 = 0, ea1 = 0, ea2 = 0, ea3 = 0;
  if (nfull > 0) {
    ea0 = eid[p];
    ea1 = eid[p + 1];
    ea2 = eid[p + 2];
    ea3 = eid[p + 3];
  }
  for (int it = 0; it < nfull; ++it) {
    int c0 = ea0, c1 = ea1, c2 = ea2, c3 = ea3;
    p += 4;
    if (it + 1 < nfull) {
      ea0 = eid[p];
      ea1 = eid[p + 1];
      ea2 = eid[p + 2];
      ea3 = eid[p + 3];
    }
    u32x4 U0 = *(const u32x4*)(pay + (size_t)c0 * 16 + oct * 4);
    u32x4 U1 = *(const u32x4*)(pay + (size_t)c1 * 16 + oct * 4);
    u32x4 U2 = *(const u32x4*)(pay + (size_t)c2 * 16 + oct * 4);
    u32x4 U3 = *(const u32x4*)(pay + (size_t)c3 * 16 + oct * 4);
#pragma unroll
    for (int j = 0; j < 4; j++) {
      float a0, b0, a1, b1, a2, b2, a3, b3;
      unpack2(U0[j], a0, b0);
      unpack2(U1[j], a1, b1);
      unpack2(U2[j], a2, b2);
      unpack2(U3[j], a3, b3);
      int i0 = 2 * j, i1 = 2 * j + 1;
      sv[i0] += a0 + a1 + a2 + a3;
      qv[i0] += a0 * a0 + a1 * a1 + a2 * a2 + a3 * a3;
      xv[i0] = fmaxf(fmaxf(xv[i0], fmaxf(a0, a1)), fmaxf(a2, a3));
      nv[i0] = fminf(fminf(nv[i0], fminf(a0, a1)), fminf(a2, a3));
      sv[i1] += b0 + b1 + b2 + b3;
      qv[i1] += b0 * b0 + b1 * b1 + b2 * b2 + b3 * b3;
      xv[i1] = fmaxf(fmaxf(xv[i1], fmaxf(b0, b1)), fmaxf(b2, b3));
      nv[i1] = fminf(fminf(nv[i1], fminf(b0, b1)), fminf(b2, b3));
    }
  }
  for (; p < e1; ++p) {
    int e = eid[p];
    u32x4 U = *(const u32x4*)(pay + (size_t)e * 16 + oct * 4);
#pragma unroll
    for (int j = 0; j < 4; j++) {
      float a, b;
      unpack2(U[j], a, b);
      int i0 = 2 * j, i1 = 2 * j + 1;
      sv[i0] += a;
      qv[i0] += a * a;
      xv[i0] = fmaxf(xv[i0], a);
      nv[i0] = fminf(nv[i0], a);
      sv[i1] += b;
      qv[i1] += b * b;
      xv[i1] = fmaxf(xv[i1], b);
      nv[i1] = fminf(nv[i1], b);
    }
  }

  float degr = (float)(e1 - e0);
  float deg = fmaxf(degr, 1.f);
  float inv = 1.f / deg;
  float amp = logf(deg + 1.f);
  float att = 1.f / (deg + 1.f);

#pragma unroll
  for (int i = 0; i < 8; i++) {
    float me = sv[i] * inv;
    float va = fmaxf(qv[i] * inv - me * me, 0.f);
    sv[i] = me;                 // mean
    qv[i] = sqrtf(va + 1e-8f);  // std
    xv[i] = (xv[i] == -INFINITY) ? 0.f : xv[i];
    nv[i] = (nv[i] == INFINITY) ? 0.f : nv[i];
  }

  f32x4 acc[4] = {{0.f, 0.f, 0.f, 0.f},
                  {0.f, 0.f, 0.f, 0.f},
                  {0.f, 0.f, 0.f, 0.f},
                  {0.f, 0.f, 0.f, 0.f}};
  float scal[3] = {1.f, amp, att};
  const bf16x8* Bp = (const bf16x8*)Wf;
#pragma unroll
  for (int kt = 0; kt < 12; kt++) {
    const float* ag = (kt < 3) ? sv : (kt < 6) ? xv : (kt < 9) ? nv : qv;
    float sc = scal[kt % 3];
    bf16x8 b0 = Bp[(kt * 4 + 0) * 64 + lane];
    bf16x8 b1 = Bp[(kt * 4 + 1) * 64 + lane];
    bf16x8 b2 = Bp[(kt * 4 + 2) * 64 + lane];
    bf16x8 b3 = Bp[(kt * 4 + 3) * 64 + lane];
    bf16x8 af;
#pragma unroll
    for (int i = 0; i < 8; i++) af[i] = f2bf(ag[i] * sc);
    acc[0] = __builtin_amdgcn_mfma_f32_16x16x32_bf16(af, b0, acc[0], 0, 0, 0);
    acc[1] = __builtin_amdgcn_mfma_f32_16x16x32_bf16(af, b1, acc[1], 0, 0, 0);
    acc[2] = __builtin_amdgcn_mfma_f32_16x16x32_bf16(af, b2, acc[2], 0, 0, 0);
    acc[3] = __builtin_amdgcn_mfma_f32_16x16x32_bf16(af, b3, acc[3], 0, 0, 0);
    __builtin_amdgcn_sched_barrier(0);
  }

#pragma unroll
  for (int ct = 0; ct < 4; ct++) {
    int ocol = ct * 16 + r;
    float bb = bias[ocol];
#pragma unroll
    for (int j = 0; j < 4; j++) {
      int orow = nb + oct * 4 + j;
      out[orow * 64 + ocol] = acc[ct][j] + bb;
    }
  }
}

extern "C" void kernel_launch(void* const* d_in, const int* in_sizes, int n_in,
                              void* d_out, int out_size, void* d_ws, size_t ws_size,
                              hipStream_t stream) {
  const float* msg = (const float*)d_in[0];
  const int* dst = (const int*)d_in[1];
  const float* W = (const float*)d_in[3];
  const float* bias = (const float*)d_in[4];
  float* out = (float*)d_out;

  unsigned int* pay = (unsigned int*)d_ws;       // NE*16 uints (64B bf16 rows)
  int* pdst = (int*)(pay + (size_t)NE * 16);     // NE
  int* eid = pdst + NE;                          // NE
  int* off = eid + NE;                           // NN+1
  int* bktcnt = off + NN + 1;                    // NBKT
  int* bktoff = bktcnt + NBKT;                   // NBKT+1
  int* bkcur = bktoff + NBKT + 1;                // NBKT
  short* Wfrag = (short*)(bkcur + NBKT);         // 24576 shorts

  k_wprep<<<96, 256, 0, stream>>>(W, Wfrag);
  k_zerob<<<1, 512, 0, stream>>>(bktcnt);
  k_bktcount<<<NCBLK, 256, 0, stream>>>(dst, bktcnt);
  k_bktscan<<<1, 512, 0, stream>>>(bktcnt, bktoff, bkcur, off);
  k_binpay<<<256, 768, 0, stream>>>(msg, dst, bkcur, pay, pdst);
  k_build<<<NBKT, 256, 0, stream>>>(pdst, bktoff, off, eid);
  k_fusedS<<<(NN / 16 + 3) / 4, 256, 0, stream>>>(pay, off, eid, Wfrag, bias, out);
}